// Round 1
// baseline (65.187 us; speedup 1.0000x reference)
//
#include <hip/hip_runtime.h>

#define BATCH 4
#define NPTS 4096
#define DF 64
#define ITILE 128
#define JSPLIT 4
#define JCHUNK (NPTS/JSPLIT)   // 1024
#define JT 32
#define NT (JCHUNK/JT)         // 32
#define AUGD 96                // augmented dim: 80 feature (5x K16) + 16 spatial (1x K16)
#define LDSPITCH 104           // 96 + 8 pad -> 208B row stride, conflict-free b128 reads

typedef short short8 __attribute__((ext_vector_type(8)));
typedef float f32x16 __attribute__((ext_vector_type(16)));

__device__ __forceinline__ unsigned short bfb(float x){
  unsigned int u = __float_as_uint(x);
  u += 0x7FFFu + ((u>>16)&1u);          // RNE
  return (unsigned short)(u>>16);
}
__device__ __forceinline__ float bff(unsigned short h){
  return __uint_as_float(((unsigned int)h)<<16);
}

// ---------------------------------------------------------------- prepass ---
// One wave per point-row: builds augI (i-side / B-operand) and augJ (j-side /
// A-operand) bf16 vectors plus fp32 norms ns (spatial) and nf1 (feature-1).
// Layout per row (96 bf16):
//  augJ: [ f2 (64) | nf2_hi,nf2_mid,nf2_lo | 0 x13 | h,h,h | l,l,l | h,h,h | l,l,l | ns_hi,ns_mid,ns_lo | 0 ]
//  augI: [ 2*f1(64) | -1,-1,-1             | 0 x13 | 2h x3 | 2h x3 | 2l x3 | 2l x3 | -1,-1,-1           | 0 ]
// => accF = 2*f1.f2 - nf2_j ; accS = 2*xs_i.xs_j - ns_j  (split-product, ~fp32)
__global__ void df_prep(const float* __restrict__ pts,
                        const float* __restrict__ f1,
                        const float* __restrict__ f2,
                        unsigned short* __restrict__ augI,
                        unsigned short* __restrict__ augJ,
                        float* __restrict__ nsA,
                        float* __restrict__ nfA)
{
  int wid = (blockIdx.x<<2) + (threadIdx.x>>6);
  int lane = threadIdx.x & 63;
  if (wid >= BATCH*NPTS) return;
  float v1 = f1[(size_t)wid*DF + lane];
  float v2 = f2[(size_t)wid*DF + lane];
  float r1 = v1*v1, r2 = v2*v2;
  #pragma unroll
  for (int s=32;s>=1;s>>=1){
    r1 += __shfl_xor(r1, s);
    r2 += __shfl_xor(r2, s);
  }
  augI[(size_t)wid*AUGD + lane] = bfb(2.0f*v1);
  augJ[(size_t)wid*AUGD + lane] = bfb(v2);
  if (lane==0){
    float px = pts[(size_t)wid*3+0]/0.05f;
    float py = pts[(size_t)wid*3+1]/0.05f;
    float pz = pts[(size_t)wid*3+2]/0.05f;
    float nss = px*px+py*py+pz*pz;
    nsA[wid]=nss; nfA[wid]=r1;
    unsigned short* tI = augI + (size_t)wid*AUGD;
    unsigned short* tJ = augJ + (size_t)wid*AUGD;
    // J: feature norm 3-way split
    unsigned short a0 = bfb(r2); float rem = r2 - bff(a0);
    unsigned short a1 = bfb(rem); rem -= bff(a1);
    unsigned short a2 = bfb(rem);
    tJ[64]=a0; tJ[65]=a1; tJ[66]=a2;
    #pragma unroll
    for (int k=67;k<80;k++) tJ[k]=0;
    unsigned short hx=bfb(px), hy=bfb(py), hz=bfb(pz);
    float lx = px-bff(hx), ly = py-bff(hy), lz = pz-bff(hz);
    unsigned short lxb=bfb(lx), lyb=bfb(ly), lzb=bfb(lz);
    tJ[80]=hx; tJ[81]=hy; tJ[82]=hz;
    tJ[83]=lxb;tJ[84]=lyb;tJ[85]=lzb;
    tJ[86]=hx; tJ[87]=hy; tJ[88]=hz;
    tJ[89]=lxb;tJ[90]=lyb;tJ[91]=lzb;
    a0 = bfb(nss); rem = nss - bff(a0);
    a1 = bfb(rem); rem -= bff(a1);
    a2 = bfb(rem);
    tJ[92]=a0; tJ[93]=a1; tJ[94]=a2; tJ[95]=0;
    // I side
    unsigned short mone = bfb(-1.0f);
    tI[64]=mone; tI[65]=mone; tI[66]=mone;
    #pragma unroll
    for (int k=67;k<80;k++) tI[k]=0;
    unsigned short h2x=bfb(2.f*px), h2y=bfb(2.f*py), h2z=bfb(2.f*pz);
    unsigned short l2x=bfb(2.f*lx), l2y=bfb(2.f*ly), l2z=bfb(2.f*lz);
    tI[80]=h2x; tI[81]=h2y; tI[82]=h2z;
    tI[83]=h2x; tI[84]=h2y; tI[85]=h2z;
    tI[86]=l2x; tI[87]=l2y; tI[88]=l2z;
    tI[89]=l2x; tI[90]=l2y; tI[91]=l2z;
    tI[92]=mone; tI[93]=mone; tI[94]=mone; tI[95]=0;
  }
}

// ------------------------------------------------------------------- main ---
// Block: 4 waves, i-tile 128 (32 rows/wave), iterates its 1024-j chunk in
// 32-j tiles. accF/accS via mfma_32x32x16_bf16 (A = j-side from LDS,
// B = i-side hoisted regs). Online-softmax sums per lane-half:
//   lP,sA (spatial: known max 0 -> p = exp(min(accS - ns_i, 0)))
//   m,lQ,sB,sC (feature: racc = min(accF, nf_i), running max m)
__global__ __launch_bounds__(256, 2)
void df_main(const unsigned short* __restrict__ augI,
             const unsigned short* __restrict__ augJ,
             const float* __restrict__ nsA,
             const float* __restrict__ nfA,
             float* __restrict__ part)
{
  __shared__ unsigned short lds[2][JT][LDSPITCH];
  const int tid = threadIdx.x;
  const int wave = tid>>6, lane = tid&63;
  const int il = lane&31, hk = lane>>5;
  const int jc = blockIdx.x, it = blockIdx.y, b = blockIdx.z;

  const int irow = it*ITILE + wave*32 + il;
  const size_t ibase = ((size_t)(b*NPTS + irow))*AUGD;
  short8 bfr[6];
  #pragma unroll
  for (int s=0;s<6;s++)
    bfr[s] = *(const short8*)(augI + ibase + s*16 + hk*8);
  const float ns_i = nsA[b*NPTS + irow];
  const float nf_i = nfA[b*NPTS + irow];

  const int j0 = jc*JCHUNK;
  const size_t jbase = (size_t)(b*NPTS + j0)*AUGD;

  // staging: 384 16B-chunks per 32x192B tile; thread -> chunk tid (+ tid+256)
  const int row1 = tid/12, c1 = tid - row1*12;
  const int g2 = tid + 256;
  const int row2 = g2/12, c2 = g2 - row2*12;

  int4 pf0, pf1;
  pf0 = *(const int4*)(augJ + jbase + row1*AUGD + c1*8);
  if (tid < 128) pf1 = *(const int4*)(augJ + jbase + row2*AUGD + c2*8);
  *(int4*)(&lds[0][row1][c1*8]) = pf0;
  if (tid < 128) *(int4*)(&lds[0][row2][c2*8]) = pf1;
  __syncthreads();

  float lP=0.f, sA=0.f, m=-1e30f, lQ=0.f, sB=0.f, sC=0.f;

  for (int t=0;t<NT;t++){
    if (t+1 < NT){                       // T14: issue next-tile loads early
      size_t tb = jbase + (size_t)(t+1)*JT*AUGD;
      pf0 = *(const int4*)(augJ + tb + row1*AUGD + c1*8);
      if (tid < 128) pf1 = *(const int4*)(augJ + tb + row2*AUGD + c2*8);
    }
    const unsigned short (*tile)[LDSPITCH] = lds[t&1];
    short8 a[6];
    #pragma unroll
    for (int s=0;s<6;s++)
      a[s] = *(const short8*)(&tile[il][s*16 + hk*8]);
    f32x16 z = {};
    f32x16 accF = __builtin_amdgcn_mfma_f32_32x32x16_bf16(a[0], bfr[0], z, 0,0,0);
    accF = __builtin_amdgcn_mfma_f32_32x32x16_bf16(a[1], bfr[1], accF,0,0,0);
    accF = __builtin_amdgcn_mfma_f32_32x32x16_bf16(a[2], bfr[2], accF,0,0,0);
    accF = __builtin_amdgcn_mfma_f32_32x32x16_bf16(a[3], bfr[3], accF,0,0,0);
    accF = __builtin_amdgcn_mfma_f32_32x32x16_bf16(a[4], bfr[4], accF,0,0,0);
    f32x16 accS = __builtin_amdgcn_mfma_f32_32x32x16_bf16(a[5], bfr[5], z,0,0,0);

    float p[16], rc[16];
    float tmax = -1e30f;
    #pragma unroll
    for (int r=0;r<16;r++){
      float sp = fminf(accS[r]-ns_i, 0.0f);     // clamped spatial score (max=0)
      float pv = __expf(sp);
      p[r]=pv;
      lP += pv;
      sA = fmaf(pv, pv, sA);
      float rf = fminf(accF[r], nf_i);          // clamped feature racc
      rc[r]=rf;
      tmax = fmaxf(tmax, rf);
    }
    float mnew = fmaxf(m, tmax);
    float sg = __expf(m - mnew);
    float sg2 = sg*sg;
    lQ *= sg; sB *= sg2; sC *= sg; m = mnew;
    #pragma unroll
    for (int r=0;r<16;r++){
      float q = __expf(rc[r]-m);
      lQ += q;
      sB = fmaf(q,q,sB);
      sC = fmaf(p[r], q, sC);
    }
    if (t+1 < NT){
      int nb = (t+1)&1;
      *(int4*)(&lds[nb][row1][c1*8]) = pf0;
      if (tid<128) *(int4*)(&lds[nb][row2][c2*8]) = pf1;
    }
    __syncthreads();
  }

  // partial set k = jc*2 + half, laid out [k][b][i][8] for coalesced reduce
  const size_t pidx = (((size_t)(jc*2 + hk))*((size_t)BATCH*NPTS)
                       + (size_t)b*NPTS + irow)*8;
  part[pidx+0]=lP; part[pidx+1]=sA; part[pidx+2]=m;
  part[pidx+3]=lQ; part[pidx+4]=sB; part[pidx+5]=sC;
}

// ----------------------------------------------------------------- reduce ---
__global__ void df_reduce(const float* __restrict__ part,
                          const float* __restrict__ w,
                          float* __restrict__ ws2)
{
  const int jb = blockIdx.x, b = blockIdx.y;
  const int tid = threadIdx.x;
  const int i = jb*256 + tid;
  const size_t stride = (size_t)BATCH*NPTS*8;
  const size_t base = ((size_t)b*NPTS + i)*8;
  float mx = -1e30f;
  #pragma unroll
  for (int k=0;k<2*JSPLIT;k++)
    mx = fmaxf(mx, part[base + (size_t)k*stride + 2]);
  float lP=0,sA=0,lQ=0,sB=0,sC=0;
  #pragma unroll
  for (int k=0;k<2*JSPLIT;k++){
    const float* pp = part + base + (size_t)k*stride;
    lP += pp[0]; sA += pp[1];
    float sg = __expf(pp[2]-mx);
    lQ += sg*pp[3]; sB += sg*sg*pp[4]; sC += sg*pp[5];
  }
  float res = sA/(lP*lP) + sB/(lQ*lQ) - 2.0f*sC/(lP*lQ);
  float acc = w[(size_t)b*NPTS + i]*res;
  __shared__ float red[256];
  red[tid]=acc; __syncthreads();
  for (int s=128;s>0;s>>=1){
    if (tid<s) red[tid]+=red[tid+s];
    __syncthreads();
  }
  if (tid==0) ws2[b*16+jb]=red[0];
}

__global__ void df_final(const float* __restrict__ ws2, float* __restrict__ out){
  int b = threadIdx.x;
  if (b < BATCH){
    float s=0.f;
    #pragma unroll
    for (int k=0;k<16;k++) s += ws2[b*16+k];
    out[b]=s;
  }
}

// ----------------------------------------------------------------- launch ---
extern "C" void kernel_launch(void* const* d_in, const int* in_sizes, int n_in,
                              void* d_out, int out_size, void* d_ws, size_t ws_size,
                              hipStream_t stream) {
  const float* pts = (const float*)d_in[0];
  const float* w   = (const float*)d_in[1];
  const float* f1  = (const float*)d_in[2];
  const float* f2  = (const float*)d_in[3];
  float* out = (float*)d_out;

  unsigned char* ws = (unsigned char*)d_ws;
  const size_t AUG_BYTES  = (size_t)BATCH*NPTS*AUGD*2;     // 3,145,728
  const size_t NORM_BYTES = (size_t)BATCH*NPTS*4;          // 65,536
  const size_t PART_BYTES = (size_t)2*JSPLIT*BATCH*NPTS*8*4; // 4,194,304
  unsigned short* augI = (unsigned short*)(ws);
  unsigned short* augJ = (unsigned short*)(ws + AUG_BYTES);
  float* nsA  = (float*)(ws + 2*AUG_BYTES);
  float* nfA  = (float*)(ws + 2*AUG_BYTES + NORM_BYTES);
  float* part = (float*)(ws + 2*AUG_BYTES + 2*NORM_BYTES);
  float* ws2  = (float*)(ws + 2*AUG_BYTES + 2*NORM_BYTES + PART_BYTES);

  df_prep<<<(BATCH*NPTS)/4, 256, 0, stream>>>(pts, f1, f2, augI, augJ, nsA, nfA);
  df_main<<<dim3(JSPLIT, NPTS/ITILE, BATCH), 256, 0, stream>>>(augI, augJ, nsA, nfA, part);
  df_reduce<<<dim3(16, BATCH), 256, 0, stream>>>(part, w, ws2);
  df_final<<<1, 64, 0, stream>>>(ws2, out);
}